// Round 11
// baseline (251.770 us; speedup 1.0000x reference)
//
#include <hip/hip_runtime.h>
#include <hip/hip_bf16.h>
#include <cstdint>

typedef unsigned char u8;
typedef float floatx4 __attribute__((ext_vector_type(4)));
typedef int intx8 __attribute__((ext_vector_type(8)));

__device__ __forceinline__ void gld_lds16(const void* g, void* l) {
    __builtin_amdgcn_global_load_lds(
        (const __attribute__((address_space(1))) unsigned int*)g,
        (__attribute__((address_space(3))) unsigned int*)l, 16, 0, 0);
}

// fp8 e4m3 (OCP) converts
__device__ __forceinline__ u8 f2fp8(float v) {
    return (u8)(__builtin_amdgcn_cvt_pk_fp8_f32(v, v, 0, false) & 0xff);
}
__device__ __forceinline__ unsigned int pack4_fp8(float a, float b, float c, float d) {
    unsigned int u = __builtin_amdgcn_cvt_pk_fp8_f32(a, b, 0, false);
    u = __builtin_amdgcn_cvt_pk_fp8_f32(c, d, u, true);
    return u;
}

// 32B fragment: two swizzled 16B granules -> v8i32
__device__ __forceinline__ intx8 ld_frag(const u8* p, int lo, int hi) {
    uint4 a = *(const uint4*)(p + lo);
    uint4 b = *(const uint4*)(p + hi);
    intx8 r;
    r[0] = a.x; r[1] = a.y; r[2] = a.z; r[3] = a.w;
    r[4] = b.x; r[5] = b.y; r[6] = b.z; r[7] = b.w;
    return r;
}

// ---------------------------------------------------------------------------
// Setup: blocks 0..511 = one-pass GroupNorm (x fp32 -> hT [B,N,C] fp8,
// transposed, register-resident); blocks 512..4607 = weight convert.
// ---------------------------------------------------------------------------
__global__ __launch_bounds__(256) void setup_kernel(
    const float* __restrict__ x, const float* __restrict__ gs,
    const float* __restrict__ gb,
    const float* __restrict__ wq, const float* __restrict__ wk,
    const float* __restrict__ wv, const float* __restrict__ wo,
    const float* __restrict__ bq, const float* __restrict__ bk,
    const float* __restrict__ bv,
    u8* __restrict__ hT, u8* __restrict__ wqkv, u8* __restrict__ wob,
    float* __restrict__ bqkv)
{
    const int t = threadIdx.x;
    if (blockIdx.x >= 512) {
        int i = (blockIdx.x - 512) * 256 + t;   // 0 .. 1048575
        if (i < 786432) {
            int which = i >> 18;
            int off = i & 262143;
            const float* src = which == 0 ? wq : which == 1 ? wk : wv;
            wqkv[i] = f2fp8(src[off]);
        } else {
            wob[i - 786432] = f2fp8(wo[i - 786432] * 262144.0f);  // x 2^18
        }
        if (i < 1536)
            bqkv[i] = i < 512 ? bq[i] : (i < 1024 ? bk[i - 512] : bv[i - 1024]);
        return;
    }
    const int b = blockIdx.x >> 5;
    const int g = blockIdx.x & 31;
    const int wave = t >> 6, lane = t & 63;
    const float4* x4 = (const float4*)(x + ((long long)b * 512 + g * 16) * 1024);

    float4 v[16];
    float s1 = 0.f, s2 = 0.f;
#pragma unroll
    for (int i = 0; i < 16; ++i) {
        v[i] = x4[i * 256 + t];
        s1 += v[i].x + v[i].y + v[i].z + v[i].w;
        s2 += v[i].x * v[i].x + v[i].y * v[i].y + v[i].z * v[i].z + v[i].w * v[i].w;
    }
#pragma unroll
    for (int m = 32; m; m >>= 1) {
        s1 += __shfl_xor(s1, m, 64);
        s2 += __shfl_xor(s2, m, 64);
    }
    __shared__ float red[2][4];
    __shared__ float stats[2];
    if (lane == 0) { red[0][wave] = s1; red[1][wave] = s2; }
    __syncthreads();
    if (t == 0) {
        float a = red[0][0] + red[0][1] + red[0][2] + red[0][3];
        float q = red[1][0] + red[1][1] + red[1][2] + red[1][3];
        float mu = a * (1.0f / 16384.0f);
        float var = q * (1.0f / 16384.0f) - mu * mu;
        stats[0] = mu;
        stats[1] = rsqrtf(var + 1e-5f);
    }
    __syncthreads();
    const float mu = stats[0], rs = stats[1];

#pragma unroll
    for (int i = 0; i < 16; ++i) {
        const float sc = gs[g * 16 + i] * rs;
        const float bi = gb[g * 16 + i] - mu * sc;
        v[i].x = v[i].x * sc + bi;
        v[i].y = v[i].y * sc + bi;
        v[i].z = v[i].z * sc + bi;
        v[i].w = v[i].w * sc + bi;
    }
    u8* hb = hT + (long long)b * 524288 + g * 16;
#pragma unroll
    for (int r = 0; r < 4; ++r) {
        uint4 o;
        o.x = pack4_fp8(v[0][r],  v[1][r],  v[2][r],  v[3][r]);
        o.y = pack4_fp8(v[4][r],  v[5][r],  v[6][r],  v[7][r]);
        o.z = pack4_fp8(v[8][r],  v[9][r],  v[10][r], v[11][r]);
        o.w = pack4_fp8(v[12][r], v[13][r], v[14][r], v[15][r]);
        *(uint4*)(hb + (long long)(4 * t + r) * 512) = o;
    }
}

// ---------------------------------------------------------------------------
// MX fp8 NT GEMM (128x128 tile, 4 waves 64x64, BK=128, 2-barrier loop).
// EPI: 1 = fused QKV fp8 (+bias, v transposed); 3 = fp32 *scale + bias[row]+resid
// ---------------------------------------------------------------------------
template <int EPI>
__global__ __launch_bounds__(256, 3) void gemm_mx(
    const u8* __restrict__ A, long long sA,
    const u8* __restrict__ B, long long sB,
    void* __restrict__ C, long long sC,
    void* __restrict__ C2, void* __restrict__ C3,
    int ldC, int K,
    const float* __restrict__ bias,
    const float* __restrict__ resid, long long sR,
    float scale)
{
    __shared__ __align__(16) u8 smem[33792];
    const int tid = threadIdx.x;
    const int l = tid & 63;
    const int wave = tid >> 6;
    const int wm = wave >> 1, wn = wave & 1;
    const int bm = blockIdx.x, bn = blockIdx.y, b = blockIdx.z;

    const u8* Ab = A + (long long)b * sA + (long long)bm * 128 * K;
    const u8* Bb = B + (long long)b * sB + (long long)bn * 128 * K;

    const int srow = wave * 8 + (l >> 3);
    const int sg = ((l & 7) ^ ((l >> 3) & 7)) * 16;
    const u8* ga  = Ab + (long long)srow * K + sg;
    const u8* gbp = Bb + (long long)srow * K + sg;
    const long long c32 = (long long)32 * K;
    const int ldst = wave * 1024;

    const int q4 = l >> 4;
    const int glo = ((2 * q4) ^ (l & 7)) * 16;
    const int ghi = ((2 * q4 + 1) ^ (l & 7)) * 16;
    int arow[4], brow[4];
#pragma unroll
    for (int i = 0; i < 4; ++i) {
        arow[i] = (wm * 64 + i * 16 + (l & 15)) * 128;
        brow[i] = (wn * 64 + i * 16 + (l & 15)) * 128 + 16384;
    }

    floatx4 acc[4][4] = {};
    const int niter = K >> 7;

    for (int it = 0; it < niter; ++it) {
        const int k0 = it << 7;
#pragma unroll
        for (int c = 0; c < 4; ++c) {
            gld_lds16(ga + c * c32 + k0, smem + c * 4096 + ldst);
            gld_lds16(gbp + c * c32 + k0, smem + 16384 + c * 4096 + ldst);
        }
        __syncthreads();
        intx8 bfr[4];
#pragma unroll
        for (int j = 0; j < 4; ++j) bfr[j] = ld_frag(smem + brow[j], glo, ghi);
#pragma unroll
        for (int i = 0; i < 4; ++i) {
            intx8 af = ld_frag(smem + arow[i], glo, ghi);
#pragma unroll
            for (int j = 0; j < 4; ++j)
                acc[i][j] = __builtin_amdgcn_mfma_scale_f32_16x16x128_f8f6f4(
                    af, bfr[j], acc[i][j], 0, 0, 0, 127, 0, 127);
        }
        __syncthreads();
    }

    if (EPI == 3) {
        float* Cf = (float*)C;
#pragma unroll
        for (int i = 0; i < 4; ++i) {
            const int mrow = bm * 128 + wm * 64 + i * 16 + q4 * 4;
#pragma unroll
            for (int j = 0; j < 4; ++j) {
                const int ncol = bn * 128 + wn * 64 + j * 16 + (l & 15);
#pragma unroll
                for (int r = 0; r < 4; ++r) {
                    const int row = mrow + r;
                    float v = acc[i][j][r] * scale + bias[row] +
                              resid[(long long)b * sR + (long long)row * ldC + ncol];
                    Cf[(long long)b * sC + (long long)row * ldC + ncol] = v;
                }
            }
        }
    } else {   // EPI == 1: fused QKV
        const int which = bn >> 2;     // 0=q 1=k 2=v
        u8* tile = smem;               // 128 x 144 fp8
#pragma unroll
        for (int i = 0; i < 4; ++i) {
            const int rl = wm * 64 + i * 16 + q4 * 4;
#pragma unroll
            for (int j = 0; j < 4; ++j) {
                const int cl = wn * 64 + j * 16 + (l & 15);
                const float badd = bias[bn * 128 + cl];
                if (which == 2) {
                    *(unsigned int*)(tile + cl * 144 + rl) =
                        pack4_fp8(acc[i][j][0] + badd, acc[i][j][1] + badd,
                                  acc[i][j][2] + badd, acc[i][j][3] + badd);
                } else {
#pragma unroll
                    for (int r = 0; r < 4; ++r)
                        tile[(rl + r) * 144 + cl] = f2fp8(acc[i][j][r] + badd);
                }
            }
        }
        __syncthreads();
        const int slot = (tid & 7) * 16;
#pragma unroll
        for (int p = 0; p < 4; ++p) {
            const int row = p * 32 + (tid >> 3);
            uint4 d = *(const uint4*)(tile + row * 144 + slot);
            u8* dst;
            if (which == 0)
                dst = (u8*)C + (long long)b * sC + (long long)(bm * 128 + row) * 512
                      + (bn & 3) * 128 + slot;
            else if (which == 1)
                dst = (u8*)C2 + (long long)b * sC + (long long)(bm * 128 + row) * 512
                      + (bn & 3) * 128 + slot;
            else
                dst = (u8*)C3 + (long long)b * sC + (long long)((bn & 3) * 128 + row) * 1024
                      + bm * 128 + slot;
            *(uint4*)dst = d;
        }
    }
}

// ---------------------------------------------------------------------------
// Fused flash attention (no-max softmax, exact sums):
// hvT[n,c] = (1/lsum[n]) * sum_m exp(q.k/sqrt(C)) * v[c,m]
// Block: 64 q-rows (bm), batch b. 4 waves x 16 rows. Loop 8 m-tiles of 128.
// Per m-tile: S^T = k.q^T via MX MFMA (A=k rows m, B=q rows n) -> exp ->
// packed u32 writes into per-wave S_lds [16 n][128 m] -> PV (A=P, B=v).
// lsum accumulated exactly in registers (wave owns its rows; no atomics).
// LDS: q[0,32K) | stage[32K,64K) 2x16KB | S_lds[64K,72K) 4x2KB. 72KB/block.
// ---------------------------------------------------------------------------
__global__ __launch_bounds__(256, 2) void attn_fused(
    const u8* __restrict__ q, const u8* __restrict__ k,
    const u8* __restrict__ v, u8* __restrict__ hvT)
{
    __shared__ __align__(16) u8 smem[73728];
    const int tid = threadIdx.x;
    const int l = tid & 63;
    const int wave = tid >> 6;
    const int qq = l >> 4;
    const int bm = blockIdx.x, b = blockIdx.y;
    const u8* qb = q + (long long)b * 524288;
    const u8* kb = k + (long long)b * 524288;
    const u8* vb = v + (long long)b * 524288;
    const float SC = 0.044194173824159216f;   // 1/sqrt(512)

    // stage q rows bm*64..+63 (32 KB), swizzled granules per row
    {
        const int rbase = wave * 2 + (l >> 5);
        const int cc = (l >> 3) & 3;
        const int s = l & 7;
#pragma unroll
        for (int c = 0; c < 8; ++c) {
            const int row = c * 8 + rbase;
            const int g = s ^ (row & 7);
            gld_lds16(qb + (long long)(bm * 64 + row) * 512 + cc * 128 + g * 16,
                      smem + c * 4096 + wave * 1024);
        }
    }

    const int glo = ((2 * qq) ^ (l & 7)) * 16;
    const int ghi = ((2 * qq + 1) ^ (l & 7)) * 16;
    const int srow = wave * 8 + (l >> 3);
    const int fg = ((l & 7) ^ ((l >> 3) & 7)) * 16;
    u8* stg = smem + 32768;
    u8* slds = smem + 65536 + wave * 2048;
    const int qrow = (wave * 16 + (l & 15)) * 512;   // q frag base (row-major 512B)

    floatx4 oacc[32] = {};
    float lpart = 0.f;

    for (int mt = 0; mt < 8; ++mt) {
        const int m0 = mt * 128;
        floatx4 sacc[8] = {};
        // ---- QK: S^T[m][n] over c' chunks (2 rounds x 2 chunks) ----
#pragma unroll 1
        for (int rnd = 0; rnd < 2; ++rnd) {
#pragma unroll
            for (int h = 0; h < 2; ++h) {
                const int cc = rnd * 2 + h;
#pragma unroll
                for (int c = 0; c < 4; ++c)
                    gld_lds16(kb + (long long)(m0 + c * 32 + srow) * 512 + cc * 128 + fg,
                              stg + h * 16384 + c * 4096 + wave * 1024);
            }
            __syncthreads();
#pragma unroll
            for (int h = 0; h < 2; ++h) {
                const int cc = rnd * 2 + h;
                intx8 qf = ld_frag(smem + qrow + cc * 128, glo, ghi);
                const u8* base = stg + h * 16384;
#pragma unroll
                for (int i = 0; i < 8; ++i) {
                    intx8 af = ld_frag(base + (i * 16 + (l & 15)) * 128, glo, ghi);
                    sacc[i] = __builtin_amdgcn_mfma_scale_f32_16x16x128_f8f6f4(
                        af, qf, sacc[i], 0, 0, 0, 127, 0, 127);
                }
            }
            __syncthreads();
        }
        // ---- exp + pack into per-wave S_lds [n:l&15][m: i*16+qq*4+r] ----
#pragma unroll
        for (int i = 0; i < 8; ++i) {
            float e0 = __expf(sacc[i][0] * SC);
            float e1 = __expf(sacc[i][1] * SC);
            float e2 = __expf(sacc[i][2] * SC);
            float e3 = __expf(sacc[i][3] * SC);
            lpart += (e0 + e1) + (e2 + e3);
            *(unsigned int*)(slds + (l & 15) * 128 + ((i ^ (l & 7)) * 16) + qq * 4) =
                pack4_fp8(e0 * 0.25f, e1 * 0.25f, e2 * 0.25f, e3 * 0.25f);
        }
        intx8 pf = ld_frag(slds + (l & 15) * 128, glo, ghi);   // A-frag of P
        // ---- PV: oacc[n, 512 c] += P . v^T over c chunks ----
#pragma unroll 1
        for (int rnd = 0; rnd < 2; ++rnd) {
#pragma unroll
            for (int h = 0; h < 2; ++h) {
                const int c0 = (rnd * 2 + h) * 128;
#pragma unroll
                for (int c = 0; c < 4; ++c)
                    gld_lds16(vb + (long long)(c0 + c * 32 + srow) * 1024 + m0 + fg,
                              stg + h * 16384 + c * 4096 + wave * 1024);
            }
            __syncthreads();
#pragma unroll
            for (int h = 0; h < 2; ++h) {
                const int cch = rnd * 2 + h;
                const u8* base = stg + h * 16384;
#pragma unroll
                for (int j = 0; j < 8; ++j) {
                    intx8 bf = ld_frag(base + (j * 16 + (l & 15)) * 128, glo, ghi);
                    oacc[cch * 8 + j] = __builtin_amdgcn_mfma_scale_f32_16x16x128_f8f6f4(
                        pf, bf, oacc[cch * 8 + j], 0, 0, 0, 127, 0, 127);
                }
            }
            __syncthreads();
        }
    }

    // ---- normalize + output ----
    lpart += __shfl_xor(lpart, 16, 64);
    lpart += __shfl_xor(lpart, 32, 64);      // lsum for n = l&15 (all qq copies)
    float rn[4];
#pragma unroll
    for (int r = 0; r < 4; ++r)
        rn[r] = 4.0f / __shfl(lpart, qq * 4 + r, 64);   // lsum for n = qq*4+r

    // fill hvT tile [64 n][512 c] in smem (q region, no longer read)
#pragma unroll
    for (int t32 = 0; t32 < 32; ++t32) {
        const int cbyte = (t32 >> 3) * 128 + (t32 & 7) * 16 + (l & 15);
        const int nb = (wave * 16 + qq * 4) * 512 + cbyte;
#pragma unroll
        for (int r = 0; r < 4; ++r)
            smem[nb + r * 512] = f2fp8(oacc[t32][r] * rn[r]);
    }
    __syncthreads();
    const int rrow = tid >> 5;
    const int cb16 = (tid & 31) * 16;
    u8* hb = hvT + (long long)b * 524288 + (long long)bm * 64 * 512;
#pragma unroll
    for (int c = 0; c < 8; ++c) {
        const int rr = c * 8 + rrow;
        uint4 d = *(const uint4*)(smem + rr * 512 + cb16);
        *(uint4*)(hb + rr * 512 + cb16) = d;
    }
}

// ---------------------------------------------------------------------------
extern "C" void kernel_launch(void* const* d_in, const int* in_sizes, int n_in,
                              void* d_out, int out_size, void* d_ws, size_t ws_size,
                              hipStream_t stream)
{
    const float* x  = (const float*)d_in[0];
    const float* gs = (const float*)d_in[1];
    const float* gb = (const float*)d_in[2];
    const float* wq = (const float*)d_in[3];
    const float* bq = (const float*)d_in[4];
    const float* wk = (const float*)d_in[5];
    const float* bk = (const float*)d_in[6];
    const float* wv = (const float*)d_in[7];
    const float* bv = (const float*)d_in[8];
    const float* wo = (const float*)d_in[9];
    const float* bo = (const float*)d_in[10];
    float* out = (float*)d_out;

    u8* p = (u8*)d_ws;
    u8* hT   = p; p += 8388608;            // [B,N,C] fp8
    u8* q    = p; p += 8388608;            // [B,N,C] fp8
    u8* k    = p; p += 8388608;            // [B,N,C] fp8
    u8* v    = p; p += 8388608;            // [B,C,N] fp8
    u8* wqkv = p; p += 786432;             // [1536,512] fp8
    float* bqkv = (float*)p; p += 6144;    // [1536]
    u8* wob  = p; p += 262144;             // [512,512] fp8 (x 2^18)
    u8* hvT  = p; p += 8388608;            // [B,N,C] fp8

    // GN (blocks 0..511) + weight convert (512..4607)
    setup_kernel<<<4608, 256, 0, stream>>>(x, gs, gb, wq, wk, wv, wo, bq, bk, bv,
                                           hT, wqkv, wob, bqkv);
    // fused qkv: [1024 x 1536] = hT . wqkv^T, K=512; fp8 in/out
    gemm_mx<1><<<dim3(8, 12, 16), 256, 0, stream>>>(
        hT, 524288LL, wqkv, 0LL, q, 524288LL, k, v,
        512, 512, bqkv, nullptr, 0LL, 1.0f);
    // fused attention: QK -> exp -> PV -> normalize, hvT fp8
    attn_fused<<<dim3(16, 16), 256, 0, stream>>>(q, k, v, hvT);
    // out = (wo_s . hvT^T) * 2^-18 + bo + x  [512 x 1024] fp32, K=512
    gemm_mx<3><<<dim3(4, 8, 16), 256, 0, stream>>>(
        wob, 0LL, hvT, 524288LL, out, 524288LL, nullptr, nullptr,
        1024, 512, bo, x, 524288LL, 3.814697265625e-06f);
}

// Round 12
// 188.787 us; speedup vs baseline: 1.3336x; 1.3336x over previous
//
#include <hip/hip_runtime.h>
#include <hip/hip_bf16.h>
#include <cstdint>

typedef unsigned char u8;
typedef float floatx4 __attribute__((ext_vector_type(4)));
typedef int intx8 __attribute__((ext_vector_type(8)));

__device__ __forceinline__ void gld_lds16(const void* g, void* l) {
    __builtin_amdgcn_global_load_lds(
        (const __attribute__((address_space(1))) unsigned int*)g,
        (__attribute__((address_space(3))) unsigned int*)l, 16, 0, 0);
}

// fp8 e4m3 (OCP) converts
__device__ __forceinline__ u8 f2fp8(float v) {
    return (u8)(__builtin_amdgcn_cvt_pk_fp8_f32(v, v, 0, false) & 0xff);
}
__device__ __forceinline__ unsigned int pack4_fp8(float a, float b, float c, float d) {
    unsigned int u = __builtin_amdgcn_cvt_pk_fp8_f32(a, b, 0, false);
    u = __builtin_amdgcn_cvt_pk_fp8_f32(c, d, u, true);
    return u;
}

// 32B fragment: two swizzled 16B granules -> v8i32
__device__ __forceinline__ intx8 ld_frag(const u8* p, int lo, int hi) {
    uint4 a = *(const uint4*)(p + lo);
    uint4 b = *(const uint4*)(p + hi);
    intx8 r;
    r[0] = a.x; r[1] = a.y; r[2] = a.z; r[3] = a.w;
    r[4] = b.x; r[5] = b.y; r[6] = b.z; r[7] = b.w;
    return r;
}

// ---------------------------------------------------------------------------
// Setup: blocks 0..511 = one-pass GroupNorm (x fp32 -> hT [B,N,C] fp8,
// transposed, register-resident); blocks 512..4607 = weight convert.
// ---------------------------------------------------------------------------
__global__ __launch_bounds__(256) void setup_kernel(
    const float* __restrict__ x, const float* __restrict__ gs,
    const float* __restrict__ gb,
    const float* __restrict__ wq, const float* __restrict__ wk,
    const float* __restrict__ wv, const float* __restrict__ wo,
    const float* __restrict__ bq, const float* __restrict__ bk,
    const float* __restrict__ bv,
    u8* __restrict__ hT, u8* __restrict__ wqkv, u8* __restrict__ wob,
    float* __restrict__ bqkv)
{
    const int t = threadIdx.x;
    if (blockIdx.x >= 512) {
        int i = (blockIdx.x - 512) * 256 + t;   // 0 .. 1048575
        if (i < 786432) {
            int which = i >> 18;
            int off = i & 262143;
            const float* src = which == 0 ? wq : which == 1 ? wk : wv;
            wqkv[i] = f2fp8(src[off]);
        } else {
            wob[i - 786432] = f2fp8(wo[i - 786432] * 262144.0f);  // x 2^18
        }
        if (i < 1536)
            bqkv[i] = i < 512 ? bq[i] : (i < 1024 ? bk[i - 512] : bv[i - 1024]);
        return;
    }
    const int b = blockIdx.x >> 5;
    const int g = blockIdx.x & 31;
    const int wave = t >> 6, lane = t & 63;
    const float4* x4 = (const float4*)(x + ((long long)b * 512 + g * 16) * 1024);

    float4 v[16];
    float s1 = 0.f, s2 = 0.f;
#pragma unroll
    for (int i = 0; i < 16; ++i) {
        v[i] = x4[i * 256 + t];
        s1 += v[i].x + v[i].y + v[i].z + v[i].w;
        s2 += v[i].x * v[i].x + v[i].y * v[i].y + v[i].z * v[i].z + v[i].w * v[i].w;
    }
#pragma unroll
    for (int m = 32; m; m >>= 1) {
        s1 += __shfl_xor(s1, m, 64);
        s2 += __shfl_xor(s2, m, 64);
    }
    __shared__ float red[2][4];
    __shared__ float stats[2];
    if (lane == 0) { red[0][wave] = s1; red[1][wave] = s2; }
    __syncthreads();
    if (t == 0) {
        float a = red[0][0] + red[0][1] + red[0][2] + red[0][3];
        float q = red[1][0] + red[1][1] + red[1][2] + red[1][3];
        float mu = a * (1.0f / 16384.0f);
        float var = q * (1.0f / 16384.0f) - mu * mu;
        stats[0] = mu;
        stats[1] = rsqrtf(var + 1e-5f);
    }
    __syncthreads();
    const float mu = stats[0], rs = stats[1];

#pragma unroll
    for (int i = 0; i < 16; ++i) {
        const float sc = gs[g * 16 + i] * rs;
        const float bi = gb[g * 16 + i] - mu * sc;
        v[i].x = v[i].x * sc + bi;
        v[i].y = v[i].y * sc + bi;
        v[i].z = v[i].z * sc + bi;
        v[i].w = v[i].w * sc + bi;
    }
    u8* hb = hT + (long long)b * 524288 + g * 16;
#pragma unroll
    for (int r = 0; r < 4; ++r) {
        uint4 o;
        o.x = pack4_fp8(v[0][r],  v[1][r],  v[2][r],  v[3][r]);
        o.y = pack4_fp8(v[4][r],  v[5][r],  v[6][r],  v[7][r]);
        o.z = pack4_fp8(v[8][r],  v[9][r],  v[10][r], v[11][r]);
        o.w = pack4_fp8(v[12][r], v[13][r], v[14][r], v[15][r]);
        *(uint4*)(hb + (long long)(4 * t + r) * 512) = o;
    }
}

// ---------------------------------------------------------------------------
// MX fp8 NT GEMM (128x128 tile, 4 waves 64x64, BK=128, 2-barrier loop).
// EPI: 1 = fused QKV fp8 (+bias, v transposed); 3 = fp32 *scale + bias[row]+resid
// ---------------------------------------------------------------------------
template <int EPI>
__global__ __launch_bounds__(256, 3) void gemm_mx(
    const u8* __restrict__ A, long long sA,
    const u8* __restrict__ B, long long sB,
    void* __restrict__ C, long long sC,
    void* __restrict__ C2, void* __restrict__ C3,
    int ldC, int K,
    const float* __restrict__ bias,
    const float* __restrict__ resid, long long sR,
    float scale)
{
    __shared__ __align__(16) u8 smem[33792];
    const int tid = threadIdx.x;
    const int l = tid & 63;
    const int wave = tid >> 6;
    const int wm = wave >> 1, wn = wave & 1;
    const int bm = blockIdx.x, bn = blockIdx.y, b = blockIdx.z;

    const u8* Ab = A + (long long)b * sA + (long long)bm * 128 * K;
    const u8* Bb = B + (long long)b * sB + (long long)bn * 128 * K;

    const int srow = wave * 8 + (l >> 3);
    const int sg = ((l & 7) ^ ((l >> 3) & 7)) * 16;
    const u8* ga  = Ab + (long long)srow * K + sg;
    const u8* gbp = Bb + (long long)srow * K + sg;
    const long long c32 = (long long)32 * K;
    const int ldst = wave * 1024;

    const int q4 = l >> 4;
    const int glo = ((2 * q4) ^ (l & 7)) * 16;
    const int ghi = ((2 * q4 + 1) ^ (l & 7)) * 16;
    int arow[4], brow[4];
#pragma unroll
    for (int i = 0; i < 4; ++i) {
        arow[i] = (wm * 64 + i * 16 + (l & 15)) * 128;
        brow[i] = (wn * 64 + i * 16 + (l & 15)) * 128 + 16384;
    }

    floatx4 acc[4][4] = {};
    const int niter = K >> 7;

    for (int it = 0; it < niter; ++it) {
        const int k0 = it << 7;
#pragma unroll
        for (int c = 0; c < 4; ++c) {
            gld_lds16(ga + c * c32 + k0, smem + c * 4096 + ldst);
            gld_lds16(gbp + c * c32 + k0, smem + 16384 + c * 4096 + ldst);
        }
        __syncthreads();
        intx8 bfr[4];
#pragma unroll
        for (int j = 0; j < 4; ++j) bfr[j] = ld_frag(smem + brow[j], glo, ghi);
#pragma unroll
        for (int i = 0; i < 4; ++i) {
            intx8 af = ld_frag(smem + arow[i], glo, ghi);
#pragma unroll
            for (int j = 0; j < 4; ++j)
                acc[i][j] = __builtin_amdgcn_mfma_scale_f32_16x16x128_f8f6f4(
                    af, bfr[j], acc[i][j], 0, 0, 0, 127, 0, 127);
        }
        __syncthreads();
    }

    if (EPI == 3) {
        float* Cf = (float*)C;
#pragma unroll
        for (int i = 0; i < 4; ++i) {
            const int mrow = bm * 128 + wm * 64 + i * 16 + q4 * 4;
#pragma unroll
            for (int j = 0; j < 4; ++j) {
                const int ncol = bn * 128 + wn * 64 + j * 16 + (l & 15);
#pragma unroll
                for (int r = 0; r < 4; ++r) {
                    const int row = mrow + r;
                    float v = acc[i][j][r] * scale + bias[row] +
                              resid[(long long)b * sR + (long long)row * ldC + ncol];
                    Cf[(long long)b * sC + (long long)row * ldC + ncol] = v;
                }
            }
        }
    } else {   // EPI == 1: fused QKV
        const int which = bn >> 2;     // 0=q 1=k 2=v
        u8* tile = smem;               // 128 x 144 fp8
#pragma unroll
        for (int i = 0; i < 4; ++i) {
            const int rl = wm * 64 + i * 16 + q4 * 4;
#pragma unroll
            for (int j = 0; j < 4; ++j) {
                const int cl = wn * 64 + j * 16 + (l & 15);
                const float badd = bias[bn * 128 + cl];
                if (which == 2) {
                    *(unsigned int*)(tile + cl * 144 + rl) =
                        pack4_fp8(acc[i][j][0] + badd, acc[i][j][1] + badd,
                                  acc[i][j][2] + badd, acc[i][j][3] + badd);
                } else {
#pragma unroll
                    for (int r = 0; r < 4; ++r)
                        tile[(rl + r) * 144 + cl] = f2fp8(acc[i][j][r] + badd);
                }
            }
        }
        __syncthreads();
        const int slot = (tid & 7) * 16;
#pragma unroll
        for (int p = 0; p < 4; ++p) {
            const int row = p * 32 + (tid >> 3);
            uint4 d = *(const uint4*)(tile + row * 144 + slot);
            u8* dst;
            if (which == 0)
                dst = (u8*)C + (long long)b * sC + (long long)(bm * 128 + row) * 512
                      + (bn & 3) * 128 + slot;
            else if (which == 1)
                dst = (u8*)C2 + (long long)b * sC + (long long)(bm * 128 + row) * 512
                      + (bn & 3) * 128 + slot;
            else
                dst = (u8*)C3 + (long long)b * sC + (long long)((bn & 3) * 128 + row) * 1024
                      + bm * 128 + slot;
            *(uint4*)dst = d;
        }
    }
}

// ---------------------------------------------------------------------------
// Fused flash attention (no-max softmax, exact sums):
// hvT[n,c] = (1/lsum[n]) * sum_m exp(q.k/sqrt(C)) * v[c,m]
// Block: 64 q-rows (bm), batch b. 4 waves x 16 rows. Loop 8 m-tiles of 128.
// ALL inner loops fully unrolled -> every acc index is compile-time constant
// (R11's `#pragma unroll 1` made oacc[] dynamically indexed -> 300 MB of
// scratch spill traffic; that was the 120 us).
// LDS: q[0,32K) | stage[32K,64K) 2x16KB | S_lds[64K,72K) 4x2KB. 72KB/block.
// ---------------------------------------------------------------------------
__global__ __launch_bounds__(256, 2) void attn_fused(
    const u8* __restrict__ q, const u8* __restrict__ k,
    const u8* __restrict__ v, u8* __restrict__ hvT)
{
    __shared__ __align__(16) u8 smem[73728];
    const int tid = threadIdx.x;
    const int l = tid & 63;
    const int wave = tid >> 6;
    const int qq = l >> 4;
    const int bm = blockIdx.x, b = blockIdx.y;
    const u8* qb = q + (long long)b * 524288;
    const u8* kb = k + (long long)b * 524288;
    const u8* vb = v + (long long)b * 524288;
    const float SC = 0.044194173824159216f;   // 1/sqrt(512)

    // stage q rows bm*64..+63 (32 KB), swizzled granules per row
    {
        const int rbase = wave * 2 + (l >> 5);
        const int cc = (l >> 3) & 3;
        const int s = l & 7;
#pragma unroll
        for (int c = 0; c < 8; ++c) {
            const int row = c * 8 + rbase;
            const int g = s ^ (row & 7);
            gld_lds16(qb + (long long)(bm * 64 + row) * 512 + cc * 128 + g * 16,
                      smem + c * 4096 + wave * 1024);
        }
    }

    const int glo = ((2 * qq) ^ (l & 7)) * 16;
    const int ghi = ((2 * qq + 1) ^ (l & 7)) * 16;
    const int srow = wave * 8 + (l >> 3);
    const int fg = ((l & 7) ^ ((l >> 3) & 7)) * 16;
    u8* stg = smem + 32768;
    u8* slds = smem + 65536 + wave * 2048;
    const int qrow = (wave * 16 + (l & 15)) * 512;   // q frag base (row-major 512B)

    floatx4 oacc[32] = {};
    float lpart = 0.f;

    for (int mt = 0; mt < 8; ++mt) {
        const int m0 = mt * 128;
        floatx4 sacc[8] = {};
        // ---- QK: S^T[m][n] over 4 c'-chunks (2 rounds x 2 chunks, unrolled) ----
#pragma unroll
        for (int rnd = 0; rnd < 2; ++rnd) {
#pragma unroll
            for (int h = 0; h < 2; ++h) {
                const int cc = rnd * 2 + h;
#pragma unroll
                for (int c = 0; c < 4; ++c)
                    gld_lds16(kb + (long long)(m0 + c * 32 + srow) * 512 + cc * 128 + fg,
                              stg + h * 16384 + c * 4096 + wave * 1024);
            }
            __syncthreads();
#pragma unroll
            for (int h = 0; h < 2; ++h) {
                const int cc = rnd * 2 + h;
                intx8 qf = ld_frag(smem + qrow + cc * 128, glo, ghi);
                const u8* base = stg + h * 16384;
#pragma unroll
                for (int i = 0; i < 8; ++i) {
                    intx8 af = ld_frag(base + (i * 16 + (l & 15)) * 128, glo, ghi);
                    sacc[i] = __builtin_amdgcn_mfma_scale_f32_16x16x128_f8f6f4(
                        af, qf, sacc[i], 0, 0, 0, 127, 0, 127);
                }
            }
            __syncthreads();
        }
        // ---- exp + pack into per-wave S_lds [n:l&15][m: i*16+qq*4+r] ----
#pragma unroll
        for (int i = 0; i < 8; ++i) {
            float e0 = __expf(sacc[i][0] * SC);
            float e1 = __expf(sacc[i][1] * SC);
            float e2 = __expf(sacc[i][2] * SC);
            float e3 = __expf(sacc[i][3] * SC);
            lpart += (e0 + e1) + (e2 + e3);
            *(unsigned int*)(slds + (l & 15) * 128 + ((i ^ (l & 7)) * 16) + qq * 4) =
                pack4_fp8(e0 * 0.25f, e1 * 0.25f, e2 * 0.25f, e3 * 0.25f);
        }
        intx8 pf = ld_frag(slds + (l & 15) * 128, glo, ghi);   // A-frag of P
        // ---- PV: oacc[n, 512 c] += P . v^T (2 rounds x 2 chunks, unrolled) ----
#pragma unroll
        for (int rnd = 0; rnd < 2; ++rnd) {
#pragma unroll
            for (int h = 0; h < 2; ++h) {
                const int c0 = (rnd * 2 + h) * 128;
#pragma unroll
                for (int c = 0; c < 4; ++c)
                    gld_lds16(vb + (long long)(c0 + c * 32 + srow) * 1024 + m0 + fg,
                              stg + h * 16384 + c * 4096 + wave * 1024);
            }
            __syncthreads();
#pragma unroll
            for (int h = 0; h < 2; ++h) {
                const int cch = rnd * 2 + h;
                const u8* base = stg + h * 16384;
#pragma unroll
                for (int j = 0; j < 8; ++j) {
                    intx8 bf = ld_frag(base + (j * 16 + (l & 15)) * 128, glo, ghi);
                    oacc[cch * 8 + j] = __builtin_amdgcn_mfma_scale_f32_16x16x128_f8f6f4(
                        pf, bf, oacc[cch * 8 + j], 0, 0, 0, 127, 0, 127);
                }
            }
            __syncthreads();
        }
    }

    // ---- normalize + output ----
    lpart += __shfl_xor(lpart, 16, 64);
    lpart += __shfl_xor(lpart, 32, 64);      // lsum for n = l&15 (all qq copies)
    float rn[4];
#pragma unroll
    for (int r = 0; r < 4; ++r)
        rn[r] = 4.0f / __shfl(lpart, qq * 4 + r, 64);   // lsum for n = qq*4+r

    // fill hvT tile [64 n][512 c] in smem (q region, no longer read)
#pragma unroll
    for (int t32 = 0; t32 < 32; ++t32) {
        const int cbyte = (t32 >> 3) * 128 + (t32 & 7) * 16 + (l & 15);
        const int nb = (wave * 16 + qq * 4) * 512 + cbyte;
#pragma unroll
        for (int r = 0; r < 4; ++r)
            smem[nb + r * 512] = f2fp8(oacc[t32][r] * rn[r]);
    }
    __syncthreads();
    const int rrow = tid >> 5;
    const int cb16 = (tid & 31) * 16;
    u8* hb = hvT + (long long)b * 524288 + (long long)bm * 64 * 512;
#pragma unroll
    for (int c = 0; c < 8; ++c) {
        const int rr = c * 8 + rrow;
        uint4 d = *(const uint4*)(smem + rr * 512 + cb16);
        *(uint4*)(hb + rr * 512 + cb16) = d;
    }
}

// ---------------------------------------------------------------------------
extern "C" void kernel_launch(void* const* d_in, const int* in_sizes, int n_in,
                              void* d_out, int out_size, void* d_ws, size_t ws_size,
                              hipStream_t stream)
{
    const float* x  = (const float*)d_in[0];
    const float* gs = (const float*)d_in[1];
    const float* gb = (const float*)d_in[2];
    const float* wq = (const float*)d_in[3];
    const float* bq = (const float*)d_in[4];
    const float* wk = (const float*)d_in[5];
    const float* bk = (const float*)d_in[6];
    const float* wv = (const float*)d_in[7];
    const float* bv = (const float*)d_in[8];
    const float* wo = (const float*)d_in[9];
    const float* bo = (const float*)d_in[10];
    float* out = (float*)d_out;

    u8* p = (u8*)d_ws;
    u8* hT   = p; p += 8388608;            // [B,N,C] fp8
    u8* q    = p; p += 8388608;            // [B,N,C] fp8
    u8* k    = p; p += 8388608;            // [B,N,C] fp8
    u8* v    = p; p += 8388608;            // [B,C,N] fp8
    u8* wqkv = p; p += 786432;             // [1536,512] fp8
    float* bqkv = (float*)p; p += 6144;    // [1536]
    u8* wob  = p; p += 262144;             // [512,512] fp8 (x 2^18)
    u8* hvT  = p; p += 8388608;            // [B,N,C] fp8

    // GN (blocks 0..511) + weight convert (512..4607)
    setup_kernel<<<4608, 256, 0, stream>>>(x, gs, gb, wq, wk, wv, wo, bq, bk, bv,
                                           hT, wqkv, wob, bqkv);
    // fused qkv: [1024 x 1536] = hT . wqkv^T, K=512; fp8 in/out
    gemm_mx<1><<<dim3(8, 12, 16), 256, 0, stream>>>(
        hT, 524288LL, wqkv, 0LL, q, 524288LL, k, v,
        512, 512, bqkv, nullptr, 0LL, 1.0f);
    // fused attention: QK -> exp -> PV -> normalize, hvT fp8
    attn_fused<<<dim3(16, 16), 256, 0, stream>>>(q, k, v, hvT);
    // out = (wo_s . hvT^T) * 2^-18 + bo + x  [512 x 1024] fp32, K=512
    gemm_mx<3><<<dim3(4, 8, 16), 256, 0, stream>>>(
        wob, 0LL, hvT, 524288LL, out, 524288LL, nullptr, nullptr,
        1024, 512, bo, x, 524288LL, 3.814697265625e-06f);
}